// Round 1
// baseline (1123.302 us; speedup 1.0000x reference)
//
#include <hip/hip_runtime.h>

#define BB 4
#define HH 192
#define WW 640
#define CC 32
#define SS 32

__global__ __launch_bounds__(256) void corr_kernel(
    const float* __restrict__ x, const float* __restrict__ y,
    const float* __restrict__ origin, const float* __restrict__ focal,
    const float* __restrict__ T12, float* __restrict__ out)
{
    const int w = blockIdx.x * 64 + threadIdx.x;
    const int h = blockIdx.y * 4 + threadIdx.y;
    const int b = blockIdx.z;

    const float tx = T12[b * 3 + 0];
    const float ty = T12[b * 3 + 1];
    const float tz = T12[b * 3 + 2];
    const float ox = origin[b * 2 + 0];
    const float oy = origin[b * 2 + 1];
    const float flx = focal[b * 2 + 0];
    const float fly = focal[b * 2 + 1];

    // Load this pixel's y vector (32 channels) once.
    const float* yp = y + (((size_t)b * HH + h) * WW + w) * CC;
    float4 yv[8];
#pragma unroll
    for (int i = 0; i < 8; i++) yv[i] = ((const float4*)yp)[i];

    const float* xb = x + (size_t)b * HH * WW * CC;
    float* outp = out + (((size_t)b * HH + h) * WW + w) * SS;

    const float wf = (float)w;
    const float hf = (float)h;

#pragma unroll 1
    for (int s4 = 0; s4 < SS; s4 += 4) {
        float acc4[4];
#pragma unroll
        for (int j = 0; j < 4; j++) {
            const int s = s4 + j;
            const float d = (float)s;
            // D = (d==0) ? 0 : 1/(1/d + tz)
            float D = 0.0f;
            if (s != 0) D = 1.0f / (1.0f / d + tz);
            const float Dtz = D * tz;
            const float alpha = 1.0f - Dtz;
            const float beta  = Dtz * ox + D * flx * tx;
            const float gamma = Dtz * oy + D * fly * ty;

            const float sx = alpha * wf + beta;
            const float sy = alpha * hf + gamma;
            const float x0f = floorf(sx);
            const float y0f = floorf(sy);
            const float fx = sx - x0f;
            const float fy = sy - y0f;
            const int x0 = (int)x0f;
            const int y0 = (int)y0f;
            const int x1 = x0 + 1;
            const int y1 = y0 + 1;

            const float wx0 = (x0 >= 0 && x0 < WW) ? (1.0f - fx) : 0.0f;
            const float wx1 = (x1 >= 0 && x1 < WW) ? fx : 0.0f;
            const float wy0 = (y0 >= 0 && y0 < HH) ? (1.0f - fy) : 0.0f;
            const float wy1 = (y1 >= 0 && y1 < HH) ? fy : 0.0f;

            const int cx0 = min(max(x0, 0), WW - 1);
            const int cx1 = min(max(x1, 0), WW - 1);
            const int cy0 = min(max(y0, 0), HH - 1);
            const int cy1 = min(max(y1, 0), HH - 1);

            const float w00 = wy0 * wx0;
            const float w01 = wy0 * wx1;
            const float w10 = wy1 * wx0;
            const float w11 = wy1 * wx1;

            const float4* p00 = (const float4*)(xb + ((size_t)cy0 * WW + cx0) * CC);
            const float4* p01 = (const float4*)(xb + ((size_t)cy0 * WW + cx1) * CC);
            const float4* p10 = (const float4*)(xb + ((size_t)cy1 * WW + cx0) * CC);
            const float4* p11 = (const float4*)(xb + ((size_t)cy1 * WW + cx1) * CC);

            float acc = 0.0f;
#pragma unroll
            for (int i = 0; i < 8; i++) {
                const float4 a = p00[i];
                const float4 bq = p01[i];
                const float4 c = p10[i];
                const float4 dq = p11[i];
                const float4 yy = yv[i];
                acc += (w00 * a.x + w01 * bq.x + w10 * c.x + w11 * dq.x) * yy.x;
                acc += (w00 * a.y + w01 * bq.y + w10 * c.y + w11 * dq.y) * yy.y;
                acc += (w00 * a.z + w01 * bq.z + w10 * c.z + w11 * dq.z) * yy.z;
                acc += (w00 * a.w + w01 * bq.w + w10 * c.w + w11 * dq.w) * yy.w;
            }
            acc4[j] = acc * (1.0f / 32.0f);
        }
        *(float4*)(outp + s4) = make_float4(acc4[0], acc4[1], acc4[2], acc4[3]);
    }
}

extern "C" void kernel_launch(void* const* d_in, const int* in_sizes, int n_in,
                              void* d_out, int out_size, void* d_ws, size_t ws_size,
                              hipStream_t stream) {
    const float* x = (const float*)d_in[0];
    const float* y = (const float*)d_in[1];
    const float* origin = (const float*)d_in[2];
    const float* focal = (const float*)d_in[3];
    const float* T12 = (const float*)d_in[4];
    float* out = (float*)d_out;

    dim3 block(64, 4, 1);
    dim3 grid(WW / 64, HH / 4, BB);
    corr_kernel<<<grid, block, 0, stream>>>(x, y, origin, focal, T12, out);
}

// Round 2
// 407.465 us; speedup vs baseline: 2.7568x; 2.7568x over previous
//
#include <hip/hip_runtime.h>

#define BB 4
#define HH 192
#define WW 640
#define CC 32
#define SS 32

// Lane mapping: wave = 8 pixel-slots x 8 channel-lanes.
// Corner gathers become 8 contiguous 128B segments per instruction
// (16 cache lines) instead of 64 scattered 16B lane accesses (64 lines).
__global__ __launch_bounds__(256, 4) void corr_kernel(
    const float* __restrict__ x, const float* __restrict__ y,
    const float* __restrict__ origin, const float* __restrict__ focal,
    const float* __restrict__ T12, float* __restrict__ out)
{
    __shared__ float sA[SS], sBx[SS], sGy[SS];

    const int lane = threadIdx.x & 63;
    const int wave = threadIdx.x >> 6;
    const int slot = lane >> 3;   // pixel within wave (0..7)
    const int cg   = lane & 7;    // channel group: floats [4cg, 4cg+4)

    const int p  = blockIdx.x * 32 + wave * 8 + slot;  // global pixel id
    const int w  = p % WW;
    const int hb = p / WW;
    const int h  = hb % HH;
    const int b  = hb / HH;      // uniform per block (32 px within one row)

    // Per-step warp coefficients: computed once per block into LDS.
    if (threadIdx.x < SS) {
        const int s = threadIdx.x;
        const float tz  = T12[b * 3 + 2];
        float D = 0.0f;
        if (s != 0) {
            const float d = (float)s;
            D = 1.0f / (1.0f / d + tz);
        }
        const float Dtz = D * tz;
        sA[s]  = 1.0f - Dtz;
        sBx[s] = Dtz * origin[b * 2 + 0] + D * focal[b * 2 + 0] * T12[b * 3 + 0];
        sGy[s] = Dtz * origin[b * 2 + 1] + D * focal[b * 2 + 1] * T12[b * 3 + 1];
    }

    // This slot's y channels (float4 per lane): fully coalesced 1KB/wave.
    const float4 yv = *(const float4*)(y + ((size_t)p * CC) + cg * 4);

    const float4* xb4 = (const float4*)(x + (size_t)b * HH * WW * CC);
    const float wf = (float)w;
    const float hf = (float)h;

    __syncthreads();

#pragma unroll 1
    for (int g = 0; g < 4; ++g) {
        float myres = 0.0f;
#pragma unroll
        for (int j = 0; j < 8; ++j) {
            const int s = g * 8 + j;
            const float alpha = sA[s];
            const float beta  = sBx[s];
            const float gamma = sGy[s];

            const float sx = alpha * wf + beta;
            const float sy = alpha * hf + gamma;
            const float x0f = floorf(sx);
            const float y0f = floorf(sy);
            const float fx = sx - x0f;
            const float fy = sy - y0f;
            const int x0 = (int)x0f;
            const int y0 = (int)y0f;
            const int x1 = x0 + 1;
            const int y1 = y0 + 1;

            const float wx0 = (x0 >= 0 && x0 < WW) ? (1.0f - fx) : 0.0f;
            const float wx1 = (x1 >= 0 && x1 < WW) ? fx : 0.0f;
            const float wy0 = (y0 >= 0 && y0 < HH) ? (1.0f - fy) : 0.0f;
            const float wy1 = (y1 >= 0 && y1 < HH) ? fy : 0.0f;

            const int cx0 = min(max(x0, 0), WW - 1);
            const int cx1 = min(max(x1, 0), WW - 1);
            const int cy0 = min(max(y0, 0), HH - 1);
            const int cy1 = min(max(y1, 0), HH - 1);

            const float w00 = wy0 * wx0;
            const float w01 = wy0 * wx1;
            const float w10 = wy1 * wx0;
            const float w11 = wy1 * wx1;

            // 4 corner loads: each is 8 slots x 128B contiguous.
            const float4 a  = xb4[(cy0 * WW + cx0) * 8 + cg];
            const float4 bq = xb4[(cy0 * WW + cx1) * 8 + cg];
            const float4 c  = xb4[(cy1 * WW + cx0) * 8 + cg];
            const float4 dq = xb4[(cy1 * WW + cx1) * 8 + cg];

            float acc;
            {
                const float bx = w00 * a.x + w01 * bq.x + w10 * c.x + w11 * dq.x;
                const float by = w00 * a.y + w01 * bq.y + w10 * c.y + w11 * dq.y;
                const float bz = w00 * a.z + w01 * bq.z + w10 * c.z + w11 * dq.z;
                const float bw = w00 * a.w + w01 * bq.w + w10 * c.w + w11 * dq.w;
                acc = bx * yv.x + by * yv.y + bz * yv.z + bw * yv.w;
            }

            // Butterfly sum over the 8 channel-lanes of this slot.
            acc += __shfl_xor(acc, 1, 64);
            acc += __shfl_xor(acc, 2, 64);
            acc += __shfl_xor(acc, 4, 64);

            if (cg == j) myres = acc * (1.0f / 32.0f);
        }
        // Lane cg stores step g*8+cg: 8 contiguous floats per slot.
        out[(size_t)p * SS + g * 8 + cg] = myres;
    }
}

extern "C" void kernel_launch(void* const* d_in, const int* in_sizes, int n_in,
                              void* d_out, int out_size, void* d_ws, size_t ws_size,
                              hipStream_t stream) {
    const float* x = (const float*)d_in[0];
    const float* y = (const float*)d_in[1];
    const float* origin = (const float*)d_in[2];
    const float* focal = (const float*)d_in[3];
    const float* T12 = (const float*)d_in[4];
    float* out = (float*)d_out;

    const int npix = BB * HH * WW;          // 491520
    dim3 block(256, 1, 1);
    dim3 grid(npix / 32, 1, 1);             // 15360 blocks, 32 px/block
    corr_kernel<<<grid, block, 0, stream>>>(x, y, origin, focal, T12, out);
}

// Round 3
// 387.685 us; speedup vs baseline: 2.8975x; 1.0510x over previous
//
#include <hip/hip_runtime.h>

#define BB 4
#define HH 192
#define WW 640
#define CC 32
#define SS 32
#define PXB 32   // pixels per block (contiguous within one row; 640 % 32 == 0)
#define SPH 16   // steps per phase (2 phases x 16 = 32 steps)

// Wave = 8 pixel-slots x 8 channel-lanes. Per-(px,step) address/weight math is
// computed ONCE in phase 1 (1024 entries / 256 threads per phase-pair) instead
// of redundantly by all 8 channel lanes every step.
__global__ __launch_bounds__(256, 4) void corr_kernel(
    const float* __restrict__ x, const float* __restrict__ y,
    const float* __restrict__ origin, const float* __restrict__ focal,
    const float* __restrict__ T12, float* __restrict__ out)
{
    __shared__ uint4  sOff[SPH * PXB];   // 4 corner byte-offsets per (s,px)
    __shared__ float4 sWt [SPH * PXB];   // 4 corner weights per (s,px)

    const int tid  = threadIdx.x;
    const int lane = tid & 63;
    const int wave = tid >> 6;
    const int slot = lane >> 3;   // pixel within wave (0..7)
    const int cg   = lane & 7;    // channel group: floats [4cg, 4cg+4)

    const int p0 = blockIdx.x * PXB;          // first pixel of block
    const int w0 = p0 % WW;                   // uniform: block stays in one row
    const int h  = (p0 / WW) % HH;
    const int b  = p0 / (WW * HH);

    // Per-batch scalars (uniform -> scalar regs)
    const float tz = T12[b * 3 + 2];
    const float kx = tz * origin[b * 2 + 0] + focal[b * 2 + 0] * T12[b * 3 + 0];
    const float ky = tz * origin[b * 2 + 1] + focal[b * 2 + 1] * T12[b * 3 + 1];

    // This lane's pixel + its y channel-group (coalesced 1KB/wave)
    const int pme = p0 + wave * 8 + slot;
    const float4 yv = *(const float4*)(y + (size_t)pme * CC + cg * 4);
    const char* xbase = (const char*)(x + (size_t)b * HH * WW * CC);

    // Phase-1 work assignment: thread t owns (px = t&31, s_loc = t>>5 and +8)
    const int e_px = tid & 31;
    const int e_s0 = tid >> 5;
    const float ewf = (float)(w0 + e_px);
    const float ehf = (float)h;

    const int cgb = cg * 16;                  // byte offset of channel group
    float* outp = out + (size_t)pme * SS;

    for (int ph = 0; ph < 2; ++ph) {
        __syncthreads();   // protect LDS from previous phase's readers
#pragma unroll
        for (int k = 0; k < 2; ++k) {
            const int s_loc = e_s0 + k * 8;
            const int s = ph * SPH + s_loc;
            float D = 0.0f;
            if (s != 0) D = 1.0f / (1.0f / (float)s + tz);
            const float alpha = 1.0f - D * tz;
            const float sx = alpha * ewf + D * kx;
            const float sy = alpha * ehf + D * ky;

            const float x0f = floorf(sx);
            const float y0f = floorf(sy);
            const float fx = sx - x0f;
            const float fy = sy - y0f;
            const int x0 = (int)x0f;
            const int y0 = (int)y0f;
            const int x1 = x0 + 1;
            const int y1 = y0 + 1;

            const float wx0 = (x0 >= 0 && x0 < WW) ? (1.0f - fx) : 0.0f;
            const float wx1 = (x1 >= 0 && x1 < WW) ? fx : 0.0f;
            const float wy0 = (y0 >= 0 && y0 < HH) ? (1.0f - fy) : 0.0f;
            const float wy1 = (y1 >= 0 && y1 < HH) ? fy : 0.0f;

            const int cx0 = min(max(x0, 0), WW - 1);
            const int cx1 = min(max(x1, 0), WW - 1);
            const int cy0 = min(max(y0, 0), HH - 1);
            const int cy1 = min(max(y1, 0), HH - 1);

            const int r0 = cy0 * WW;
            const int r1 = cy1 * WW;
            // byte offsets: (cy*W + cx) * CC * 4 = * 128
            const uint4 offs = make_uint4((unsigned)((r0 + cx0) << 7),
                                          (unsigned)((r0 + cx1) << 7),
                                          (unsigned)((r1 + cx0) << 7),
                                          (unsigned)((r1 + cx1) << 7));
            const float4 wts = make_float4(wy0 * wx0, wy0 * wx1,
                                           wy1 * wx0, wy1 * wx1);
            sOff[s_loc * PXB + e_px] = offs;
            sWt [s_loc * PXB + e_px] = wts;
        }
        __syncthreads();

        float r0 = 0.0f, r1 = 0.0f;
#pragma unroll
        for (int j = 0; j < SPH; ++j) {
            const int idx = j * PXB + wave * 8 + slot;
            const uint4  o  = sOff[idx];
            const float4 wv = sWt[idx];

            const float4 a  = *(const float4*)(xbase + (size_t)(o.x + cgb));
            const float4 bq = *(const float4*)(xbase + (size_t)(o.y + cgb));
            const float4 c  = *(const float4*)(xbase + (size_t)(o.z + cgb));
            const float4 dq = *(const float4*)(xbase + (size_t)(o.w + cgb));

            float acc;
            {
                const float bx = wv.x * a.x + wv.y * bq.x + wv.z * c.x + wv.w * dq.x;
                const float by = wv.x * a.y + wv.y * bq.y + wv.z * c.y + wv.w * dq.y;
                const float bz = wv.x * a.z + wv.y * bq.z + wv.z * c.z + wv.w * dq.z;
                const float bw = wv.x * a.w + wv.y * bq.w + wv.z * c.w + wv.w * dq.w;
                acc = bx * yv.x + by * yv.y + bz * yv.z + bw * yv.w;
            }

            // Butterfly sum over the 8 channel-lanes of this slot.
            acc += __shfl_xor(acc, 1, 64);
            acc += __shfl_xor(acc, 2, 64);
            acc += __shfl_xor(acc, 4, 64);

            if (j == cg)     r0 = acc * (1.0f / 32.0f);
            if (j == cg + 8) r1 = acc * (1.0f / 32.0f);
        }
        outp[ph * SPH + cg]     = r0;
        outp[ph * SPH + 8 + cg] = r1;
    }
}

extern "C" void kernel_launch(void* const* d_in, const int* in_sizes, int n_in,
                              void* d_out, int out_size, void* d_ws, size_t ws_size,
                              hipStream_t stream) {
    const float* x = (const float*)d_in[0];
    const float* y = (const float*)d_in[1];
    const float* origin = (const float*)d_in[2];
    const float* focal = (const float*)d_in[3];
    const float* T12 = (const float*)d_in[4];
    float* out = (float*)d_out;

    const int npix = BB * HH * WW;          // 491520
    dim3 block(256, 1, 1);
    dim3 grid(npix / PXB, 1, 1);            // 15360 blocks
    corr_kernel<<<grid, block, 0, stream>>>(x, y, origin, focal, T12, out);
}

// Round 4
// 307.650 us; speedup vs baseline: 3.6512x; 1.2601x over previous
//
#include <hip/hip_runtime.h>
#include <hip/hip_fp16.h>

#define BB 4
#define HH 192
#define WW 640
#define CC 32
#define SS 32
#define PXB 64   // pixels per block (one row segment; 640 % 64 == 0)
#define SPH 8    // steps per phase (4 phases x 8 = 32)

typedef _Float16 half2n __attribute__((ext_vector_type(2)));

#if defined(__has_builtin)
#if __has_builtin(__builtin_amdgcn_fdot2)
#define HAS_FDOT2 1
#endif
#endif

// x (fp32, 63MB) -> fp16 copy in workspace (31.5MB). Re-run every call.
__global__ __launch_bounds__(256) void convert_x_kernel(const float* __restrict__ x,
                                                        __half* __restrict__ xh) {
    const size_t i = ((size_t)blockIdx.x * 256 + threadIdx.x) * 8;
    const float4 f0 = *(const float4*)(x + i);
    const float4 f1 = *(const float4*)(x + i + 4);
    uint4 u;
    u.x = __builtin_bit_cast(unsigned, __floats2half2_rn(f0.x, f0.y));
    u.y = __builtin_bit_cast(unsigned, __floats2half2_rn(f0.z, f0.w));
    u.z = __builtin_bit_cast(unsigned, __floats2half2_rn(f1.x, f1.y));
    u.w = __builtin_bit_cast(unsigned, __floats2half2_rn(f1.z, f1.w));
    *(uint4*)(xh + i) = u;
}

// Wave = 16 pixel-slots x 4 channel-lanes (8 fp16 channels each).
// Corner-load inst: 16 slots x 64B contiguous = 1KB, 16 lines, 16 pixels.
__global__ __launch_bounds__(256, 8) void corr_kernel(
    const __half* __restrict__ xh, const float* __restrict__ y,
    const float* __restrict__ origin, const float* __restrict__ focal,
    const float* __restrict__ T12, float* __restrict__ out)
{
    __shared__ uint4 sOff[SPH * PXB];  // 4 corner byte-offsets
    __shared__ uint4 sWt [SPH * PXB];  // 4 corner weights, each packed half2(w,w)

    const int tid  = threadIdx.x;
    const int lane = tid & 63;
    const int wave = tid >> 6;
    const int slot = lane >> 2;   // pixel within wave (0..15)
    const int cg   = lane & 3;    // channel group: fp16 channels [8cg, 8cg+8)

    const int p0 = blockIdx.x * PXB;
    const int w0 = p0 % WW;
    const int h  = (p0 / WW) % HH;
    const int b  = p0 / (WW * HH);

    const float tz = T12[b * 3 + 2];
    const float kx = tz * origin[b * 2 + 0] + focal[b * 2 + 0] * T12[b * 3 + 0];
    const float ky = tz * origin[b * 2 + 1] + focal[b * 2 + 1] * T12[b * 3 + 1];

    const int pme = p0 + wave * 16 + slot;
    // This lane's 8 y channels as 4 x half2 (error 5e-4 rel, fine vs 1.8e-2 thr)
    __half2 yh[4];
    {
        const float4 ya = *(const float4*)(y + (size_t)pme * CC + cg * 8);
        const float4 yb = *(const float4*)(y + (size_t)pme * CC + cg * 8 + 4);
        yh[0] = __floats2half2_rn(ya.x, ya.y);
        yh[1] = __floats2half2_rn(ya.z, ya.w);
        yh[2] = __floats2half2_rn(yb.x, yb.y);
        yh[3] = __floats2half2_rn(yb.z, yb.w);
    }

    const char* xbase = (const char*)(xh + (size_t)b * HH * WW * CC);
    const int cgb = cg * 16;   // byte offset of channel group within 64B pixel

    // Phase-1 ownership: thread owns (e_px = tid&63, s_loc = tid>>6 and +4)
    const int e_px = tid & 63;
    const int e_s0 = tid >> 6;
    const float ewf = (float)(w0 + e_px);
    const float ehf = (float)h;

    float* outp = out + (size_t)pme * SS;

#pragma unroll 1
    for (int ph = 0; ph < 4; ++ph) {
        __syncthreads();
#pragma unroll
        for (int k = 0; k < 2; ++k) {
            const int s_loc = e_s0 + k * 4;
            const int s = ph * SPH + s_loc;
            const float sf = (float)s;
            // D = 1/(1/s + tz) = s/(1+s*tz); s=0 -> D=0 automatically.
            const float D = sf * __builtin_amdgcn_rcpf(1.0f + sf * tz);
            const float alpha = 1.0f - D * tz;
            const float sx = alpha * ewf + D * kx;
            const float sy = alpha * ehf + D * ky;

            const float x0f = floorf(sx);
            const float y0f = floorf(sy);
            const float fx = sx - x0f;
            const float fy = sy - y0f;
            const int x0 = (int)x0f;
            const int y0 = (int)y0f;
            const int x1 = x0 + 1;
            const int y1 = y0 + 1;

            const float wx0 = (x0 >= 0 && x0 < WW) ? (1.0f - fx) : 0.0f;
            const float wx1 = (x1 >= 0 && x1 < WW) ? fx : 0.0f;
            const float wy0 = (y0 >= 0 && y0 < HH) ? (1.0f - fy) : 0.0f;
            const float wy1 = (y1 >= 0 && y1 < HH) ? fy : 0.0f;

            const int cx0 = min(max(x0, 0), WW - 1);
            const int cx1 = min(max(x1, 0), WW - 1);
            const int cy0 = min(max(y0, 0), HH - 1);
            const int cy1 = min(max(y1, 0), HH - 1);

            const int r0 = cy0 * WW;
            const int r1 = cy1 * WW;
            // fp16 pixel record = 64B -> byte offset = (row*W+col) << 6
            const uint4 offs = make_uint4((unsigned)((r0 + cx0) << 6),
                                          (unsigned)((r0 + cx1) << 6),
                                          (unsigned)((r1 + cx0) << 6),
                                          (unsigned)((r1 + cx1) << 6));
            auto pk = [](float wgt) -> unsigned {
                const unsigned short us =
                    __builtin_bit_cast(unsigned short, __float2half_rn(wgt));
                return (unsigned)us * 0x10001u;   // half2(w, w)
            };
            const uint4 wts = make_uint4(pk(wy0 * wx0), pk(wy0 * wx1),
                                         pk(wy1 * wx0), pk(wy1 * wx1));
            sOff[s_loc * PXB + e_px] = offs;
            sWt [s_loc * PXB + e_px] = wts;
        }
        __syncthreads();

        float res0 = 0.0f, res1 = 0.0f;
#pragma unroll
        for (int j = 0; j < SPH; ++j) {
            const int idx = j * PXB + wave * 16 + slot;
            const uint4 o  = sOff[idx];
            const uint4 wt = sWt[idx];
            const __half2 w00 = __builtin_bit_cast(__half2, wt.x);
            const __half2 w01 = __builtin_bit_cast(__half2, wt.y);
            const __half2 w10 = __builtin_bit_cast(__half2, wt.z);
            const __half2 w11 = __builtin_bit_cast(__half2, wt.w);

            const uint4 ua = *(const uint4*)(xbase + (size_t)(o.x + cgb));
            const uint4 ub = *(const uint4*)(xbase + (size_t)(o.y + cgb));
            const uint4 uc = *(const uint4*)(xbase + (size_t)(o.z + cgb));
            const uint4 ud = *(const uint4*)(xbase + (size_t)(o.w + cgb));

            float acc = 0.0f;
#pragma unroll
            for (int i = 0; i < 4; ++i) {
                const unsigned va = (&ua.x)[i];
                const unsigned vb = (&ub.x)[i];
                const unsigned vc = (&uc.x)[i];
                const unsigned vd = (&ud.x)[i];
                __half2 comb = __hmul2(__builtin_bit_cast(__half2, va), w00);
                comb = __hfma2(__builtin_bit_cast(__half2, vb), w01, comb);
                comb = __hfma2(__builtin_bit_cast(__half2, vc), w10, comb);
                comb = __hfma2(__builtin_bit_cast(__half2, vd), w11, comb);
#ifdef HAS_FDOT2
                acc = __builtin_amdgcn_fdot2(__builtin_bit_cast(half2n, comb),
                                             __builtin_bit_cast(half2n, yh[i]),
                                             acc, false);
#else
                const float2 cf = __half22float2(comb);
                const float2 yf = __half22float2(yh[i]);
                acc += cf.x * yf.x + cf.y * yf.y;
#endif
            }

            // Reduce over the 4 channel-lanes of this slot (quad-perm DPP).
            acc += __shfl_xor(acc, 1, 64);
            acc += __shfl_xor(acc, 2, 64);

            if ((j & 3) == cg) {
                if (j < 4) res0 = acc * (1.0f / 32.0f);
                else       res1 = acc * (1.0f / 32.0f);
            }
        }
        outp[ph * SPH + cg]     = res0;
        outp[ph * SPH + 4 + cg] = res1;
    }
}

extern "C" void kernel_launch(void* const* d_in, const int* in_sizes, int n_in,
                              void* d_out, int out_size, void* d_ws, size_t ws_size,
                              hipStream_t stream) {
    const float* x = (const float*)d_in[0];
    const float* y = (const float*)d_in[1];
    const float* origin = (const float*)d_in[2];
    const float* focal = (const float*)d_in[3];
    const float* T12 = (const float*)d_in[4];
    float* out = (float*)d_out;
    __half* xh = (__half*)d_ws;   // needs BB*HH*WW*CC*2 = 31.5 MB

    const int nelem = BB * HH * WW * CC;          // 15,728,640
    convert_x_kernel<<<nelem / (256 * 8), 256, 0, stream>>>(x, xh);

    const int npix = BB * HH * WW;                // 491,520
    corr_kernel<<<npix / PXB, 256, 0, stream>>>(xh, y, origin, focal, T12, out);
}

// Round 5
// 306.746 us; speedup vs baseline: 3.6620x; 1.0029x over previous
//
#include <hip/hip_runtime.h>
#include <hip/hip_fp16.h>

#define BB 4
#define HH 192
#define WW 640
#define CC 32
#define SS 32
#define PXB 64   // pixels per block (one row segment; 640 % 64 == 0)
#define SPH 8    // steps per phase (4 phases x 8 = 32)

typedef _Float16 half2n __attribute__((ext_vector_type(2)));

#if defined(__has_builtin)
#if __has_builtin(__builtin_amdgcn_fdot2)
#define HAS_FDOT2 1
#endif
#endif

// x (fp32, 63MB) -> fp16 copy in workspace (31.5MB). Re-run every call.
__global__ __launch_bounds__(256) void convert_x_kernel(const float* __restrict__ x,
                                                        __half* __restrict__ xh) {
    const size_t i = ((size_t)blockIdx.x * 256 + threadIdx.x) * 8;
    const float4 f0 = *(const float4*)(x + i);
    const float4 f1 = *(const float4*)(x + i + 4);
    uint4 u;
    u.x = __builtin_bit_cast(unsigned, __floats2half2_rn(f0.x, f0.y));
    u.y = __builtin_bit_cast(unsigned, __floats2half2_rn(f0.z, f0.w));
    u.z = __builtin_bit_cast(unsigned, __floats2half2_rn(f1.x, f1.y));
    u.w = __builtin_bit_cast(unsigned, __floats2half2_rn(f1.z, f1.w));
    *(uint4*)(xh + i) = u;
}

// Wave = 16 pixel-slots x 4 channel-lanes (8 fp16 channels each).
// Corner-load inst: 16 slots x 64B contiguous = 1KB, 16 lines, 16 pixels.
// R5: explicit 2-deep register pipeline on the corner loads — issue step
// j+1's 4 loads before consuming step j's, so ~8 loads stay in flight and
// L2-hit latency (~200-400cyc) is covered (VGPR 24 -> ~80 by design).
__global__ __launch_bounds__(256, 6) void corr_kernel(
    const __half* __restrict__ xh, const float* __restrict__ y,
    const float* __restrict__ origin, const float* __restrict__ focal,
    const float* __restrict__ T12, float* __restrict__ out)
{
    __shared__ uint4 sOff[SPH * PXB];  // 4 corner byte-offsets
    __shared__ uint4 sWt [SPH * PXB];  // 4 corner weights, each packed half2(w,w)

    const int tid  = threadIdx.x;
    const int lane = tid & 63;
    const int wave = tid >> 6;
    const int slot = lane >> 2;   // pixel within wave (0..15)
    const int cg   = lane & 3;    // channel group: fp16 channels [8cg, 8cg+8)

    const int p0 = blockIdx.x * PXB;
    const int w0 = p0 % WW;
    const int h  = (p0 / WW) % HH;
    const int b  = p0 / (WW * HH);

    const float tz = T12[b * 3 + 2];
    const float kx = tz * origin[b * 2 + 0] + focal[b * 2 + 0] * T12[b * 3 + 0];
    const float ky = tz * origin[b * 2 + 1] + focal[b * 2 + 1] * T12[b * 3 + 1];

    const int pme = p0 + wave * 16 + slot;
    // This lane's 8 y channels as 4 x half2
    __half2 yh[4];
    {
        const float4 ya = *(const float4*)(y + (size_t)pme * CC + cg * 8);
        const float4 yb = *(const float4*)(y + (size_t)pme * CC + cg * 8 + 4);
        yh[0] = __floats2half2_rn(ya.x, ya.y);
        yh[1] = __floats2half2_rn(ya.z, ya.w);
        yh[2] = __floats2half2_rn(yb.x, yb.y);
        yh[3] = __floats2half2_rn(yb.z, yb.w);
    }

    const char* xbase = (const char*)(xh + (size_t)b * HH * WW * CC);
    const int cgb = cg * 16;   // byte offset of channel group within 64B pixel
    const int sp  = wave * 16 + slot;

    // Phase-1 ownership: thread owns (e_px = tid&63, s_loc = tid>>6 and +4)
    const int e_px = tid & 63;
    const int e_s0 = tid >> 6;
    const float ewf = (float)(w0 + e_px);
    const float ehf = (float)h;

    float* outp = out + (size_t)pme * SS;

#pragma unroll 1
    for (int ph = 0; ph < 4; ++ph) {
        __syncthreads();
#pragma unroll
        for (int k = 0; k < 2; ++k) {
            const int s_loc = e_s0 + k * 4;
            const int s = ph * SPH + s_loc;
            const float sf = (float)s;
            // D = 1/(1/s + tz) = s/(1+s*tz); s=0 -> D=0 automatically.
            const float D = sf * __builtin_amdgcn_rcpf(1.0f + sf * tz);
            const float alpha = 1.0f - D * tz;
            const float sx = alpha * ewf + D * kx;
            const float sy = alpha * ehf + D * ky;

            const float x0f = floorf(sx);
            const float y0f = floorf(sy);
            const float fx = sx - x0f;
            const float fy = sy - y0f;
            const int x0 = (int)x0f;
            const int y0 = (int)y0f;
            const int x1 = x0 + 1;
            const int y1 = y0 + 1;

            const float wx0 = (x0 >= 0 && x0 < WW) ? (1.0f - fx) : 0.0f;
            const float wx1 = (x1 >= 0 && x1 < WW) ? fx : 0.0f;
            const float wy0 = (y0 >= 0 && y0 < HH) ? (1.0f - fy) : 0.0f;
            const float wy1 = (y1 >= 0 && y1 < HH) ? fy : 0.0f;

            const int cx0 = min(max(x0, 0), WW - 1);
            const int cx1 = min(max(x1, 0), WW - 1);
            const int cy0 = min(max(y0, 0), HH - 1);
            const int cy1 = min(max(y1, 0), HH - 1);

            const int r0 = cy0 * WW;
            const int r1 = cy1 * WW;
            // fp16 pixel record = 64B -> byte offset = (row*W+col) << 6
            const uint4 offs = make_uint4((unsigned)((r0 + cx0) << 6),
                                          (unsigned)((r0 + cx1) << 6),
                                          (unsigned)((r1 + cx0) << 6),
                                          (unsigned)((r1 + cx1) << 6));
            auto pk = [](float wgt) -> unsigned {
                const unsigned short us =
                    __builtin_bit_cast(unsigned short, __float2half_rn(wgt));
                return (unsigned)us * 0x10001u;   // half2(w, w)
            };
            const uint4 wts = make_uint4(pk(wy0 * wx0), pk(wy0 * wx1),
                                         pk(wy1 * wx0), pk(wy1 * wx1));
            sOff[s_loc * PXB + e_px] = offs;
            sWt [s_loc * PXB + e_px] = wts;
        }
        __syncthreads();

        float res0 = 0.0f, res1 = 0.0f;

        // ---- software pipeline: prologue (step 0 of this phase) ----
        uint4 o  = sOff[sp];
        uint4 wt = sWt [sp];
        uint4 ua = *(const uint4*)(xbase + (size_t)(o.x + cgb));
        uint4 ub = *(const uint4*)(xbase + (size_t)(o.y + cgb));
        uint4 uc = *(const uint4*)(xbase + (size_t)(o.z + cgb));
        uint4 ud = *(const uint4*)(xbase + (size_t)(o.w + cgb));

#pragma unroll
        for (int j = 0; j < SPH; ++j) {
            uint4 o2, wt2, na, nb, nc, nd;
            if (j + 1 < SPH) {
                // issue next step's loads BEFORE consuming current registers
                o2  = sOff[(j + 1) * PXB + sp];
                wt2 = sWt [(j + 1) * PXB + sp];
                na = *(const uint4*)(xbase + (size_t)(o2.x + cgb));
                nb = *(const uint4*)(xbase + (size_t)(o2.y + cgb));
                nc = *(const uint4*)(xbase + (size_t)(o2.z + cgb));
                nd = *(const uint4*)(xbase + (size_t)(o2.w + cgb));
            }

            const __half2 w00 = __builtin_bit_cast(__half2, wt.x);
            const __half2 w01 = __builtin_bit_cast(__half2, wt.y);
            const __half2 w10 = __builtin_bit_cast(__half2, wt.z);
            const __half2 w11 = __builtin_bit_cast(__half2, wt.w);

            float acc = 0.0f;
#pragma unroll
            for (int i = 0; i < 4; ++i) {
                const unsigned va = (&ua.x)[i];
                const unsigned vb = (&ub.x)[i];
                const unsigned vc = (&uc.x)[i];
                const unsigned vd = (&ud.x)[i];
                __half2 comb = __hmul2(__builtin_bit_cast(__half2, va), w00);
                comb = __hfma2(__builtin_bit_cast(__half2, vb), w01, comb);
                comb = __hfma2(__builtin_bit_cast(__half2, vc), w10, comb);
                comb = __hfma2(__builtin_bit_cast(__half2, vd), w11, comb);
#ifdef HAS_FDOT2
                acc = __builtin_amdgcn_fdot2(__builtin_bit_cast(half2n, comb),
                                             __builtin_bit_cast(half2n, yh[i]),
                                             acc, false);
#else
                const float2 cf = __half22float2(comb);
                const float2 yf = __half22float2(yh[i]);
                acc += cf.x * yf.x + cf.y * yf.y;
#endif
            }

            // Reduce over the 4 channel-lanes (hardware quad -> DPP quad_perm).
            acc += __shfl_xor(acc, 1, 64);
            acc += __shfl_xor(acc, 2, 64);

            if ((j & 3) == cg) {
                if (j < 4) res0 = acc * (1.0f / 32.0f);
                else       res1 = acc * (1.0f / 32.0f);
            }

            if (j + 1 < SPH) {  // rotate pipeline registers (SSA under unroll)
                o = o2; wt = wt2; ua = na; ub = nb; uc = nc; ud = nd;
            }
        }
        outp[ph * SPH + cg]     = res0;
        outp[ph * SPH + 4 + cg] = res1;
    }
}

extern "C" void kernel_launch(void* const* d_in, const int* in_sizes, int n_in,
                              void* d_out, int out_size, void* d_ws, size_t ws_size,
                              hipStream_t stream) {
    const float* x = (const float*)d_in[0];
    const float* y = (const float*)d_in[1];
    const float* origin = (const float*)d_in[2];
    const float* focal = (const float*)d_in[3];
    const float* T12 = (const float*)d_in[4];
    float* out = (float*)d_out;
    __half* xh = (__half*)d_ws;   // needs BB*HH*WW*CC*2 = 31.5 MB

    const int nelem = BB * HH * WW * CC;          // 15,728,640
    convert_x_kernel<<<nelem / (256 * 8), 256, 0, stream>>>(x, xh);

    const int npix = BB * HH * WW;                // 491,520
    corr_kernel<<<npix / PXB, 256, 0, stream>>>(xh, y, origin, focal, T12, out);
}